// Round 25
// baseline (200.537 us; speedup 1.0000x reference)
//
#include <hip/hip_runtime.h>

// VectorQuantizer on MI355X — round 25: rescore fused into screen's tail
// (candidates + z rows are LDS/L2-hot; saves the rescore launch + z re-stage
// + gcnt/gcand round-trip). pre/out2/fin = r24-exact.
// z: (64,256,32,32) f32; emb: (1024,256) f32.
// out (f32): [0,16777216) z_q_out | [16777216] loss | [16777217,+65536) indices
//
// ws layout (bytes):
//   64       int      widx[65536]
//   262208   float    e2[1024]
//   266304   float    z2[65536]
//   2887744  _Float16 Ef[1024*256]
//   3412032  float    embT[256*1024]
//   4460608  double   partial[4096]

typedef _Float16 f16x8 __attribute__((ext_vector_type(8)));
typedef float f32x4 __attribute__((ext_vector_type(4)));

#define VQ_W 1.5e-3f
#define SCR_LDS_BYTES 35840

// fl32(v*v) with a barrier so the product cannot be contracted into a later add.
__device__ __forceinline__ float sq_rnd(float v) {
  float y = v * v;
  asm volatile("" : "+v"(y));
  return y;
}

// numpy pairwise_sum over 256 fp32 squared terms (8-accumulator blocks of 128).
__device__ float np_pw256_sq(const float* base, int stride) {
  float tot0, tot1;
  {
    const float* a = base;
    float r[8];
    #pragma unroll
    for (int j = 0; j < 8; ++j) r[j] = sq_rnd(a[j * stride]);
    #pragma unroll 1
    for (int i = 8; i < 128; i += 8) {
      #pragma unroll
      for (int j = 0; j < 8; ++j) r[j] += sq_rnd(a[(i + j) * stride]);
    }
    tot0 = ((r[0] + r[1]) + (r[2] + r[3])) + ((r[4] + r[5]) + (r[6] + r[7]));
  }
  {
    const float* a = base + 128 * stride;
    float r[8];
    #pragma unroll
    for (int j = 0; j < 8; ++j) r[j] = sq_rnd(a[j * stride]);
    #pragma unroll 1
    for (int i = 8; i < 128; i += 8) {
      #pragma unroll
      for (int j = 0; j < 8; ++j) r[j] += sq_rnd(a[(i + j) * stride]);
    }
    tot1 = ((r[0] + r[1]) + (r[2] + r[3])) + ((r[4] + r[5]) + (r[6] + r[7]));
  }
  return tot0 + tot1;
}

// Preprocessing (r23/r24-verified): blocks [0,1024) = emb->f16 + f32 transpose
// + e2; blocks [1024,2048) = z2 float4-vectorized chain-split (bit-exact).
__global__ __launch_bounds__(256) void vq_pre(const float* __restrict__ emb,
                                              const float* __restrict__ z,
                                              _Float16* __restrict__ Ef,
                                              float* __restrict__ embT,
                                              float* __restrict__ e2,
                                              float* __restrict__ z2) {
  __shared__ float smz[1024];  // [chain 16][point 64]
  const int tid = threadIdx.x;
  if (blockIdx.x < 1024) {
    const int g = blockIdx.x * 256 + tid;  // 0..262143
    const float v = emb[g];
    Ef[g] = (_Float16)v;                   // RNE v_cvt_f16_f32
    const int k = g >> 8, d = g & 255;
    embT[d * 1024 + k] = v;                // f32 transpose (exact copy)
    if (g < 1024) e2[g] = np_pw256_sq(emb + g * 256, 1);
    return;
  }
  const int blk = blockIdx.x - 1024;  // 0..1023, 64 points each
  const int n0 = blk * 64;
  const int bb = n0 >> 10, hw0 = n0 & 1023;
  const int slot = tid & 15;          // points slot*4..+3
  const int c = tid >> 4;             // chain 0..15
  const int dbase = (c >> 3) * 128 + (c & 7);
  const float* zb4 = z + bb * 262144 + hw0 + slot * 4;
  float r0 = 0.f, r1 = 0.f, r2 = 0.f, r3 = 0.f;
  #pragma unroll
  for (int i = 0; i < 16; ++i) {
    const float4 v = *(const float4*)&zb4[(dbase + 8 * i) * 1024];
    r0 += sq_rnd(v.x); r1 += sq_rnd(v.y); r2 += sq_rnd(v.z); r3 += sq_rnd(v.w);
  }
  smz[c * 64 + slot * 4 + 0] = r0;
  smz[c * 64 + slot * 4 + 1] = r1;
  smz[c * 64 + slot * 4 + 2] = r2;
  smz[c * 64 + slot * 4 + 3] = r3;
  __syncthreads();
  if (tid < 64) {
    const int p = tid;
    float h0[8], h1[8];
    #pragma unroll
    for (int j = 0; j < 8; ++j) {
      h0[j] = smz[j * 64 + p];
      h1[j] = smz[(8 + j) * 64 + p];
    }
    const float tot0 = ((h0[0] + h0[1]) + (h0[2] + h0[3])) +
                       ((h0[4] + h0[5]) + (h0[6] + h0[7]));
    const float tot1 = ((h1[0] + h1[1]) + (h1[2] + h1[3])) +
                       ((h1[4] + h1[5]) + (h1[6] + h1[7]));
    z2[n0 + p] = tot0 + tot1;
  }
}

// Screening v10: r20-exact MFMA main loop + FUSED rescore tail.
// Main loop (r14-verified): 64 pts/block, B direct from L2, 2-buffer register
// prefetch; chunk epilogue = exact prefix-min via one barrier (r9-verified
// superset -> cand[pt] holds all codes within W of the final screen min).
// Tail: 4 threads/point rescore candidates with the r20-exact fp32 chain
// (z re-read from L1/L2-hot rows, bit-identical values; float4 emb; u64
// (score<<10)|k LDS atomicMin => min value, lowest-k tie). c>16 -> full scan.
// Writes widx + indices output directly (gcnt/gcand globals eliminated).
__global__ __launch_bounds__(256, 4) void vq_screen(
    const float* __restrict__ z, const float* __restrict__ emb,
    const _Float16* __restrict__ Ef, const float* __restrict__ e2,
    const float* __restrict__ z2, int* __restrict__ widx,
    float* __restrict__ out) {
  extern __shared__ __align__(16) char smem[];
  // [0,32768) A; 32768 runminU[64]; 33024 cnt[64]; 33280 cand[64][16];
  // 35328 best[64] u64 (512)
  unsigned* runminU = (unsigned*)(smem + 32768);
  int* cnt = (int*)(smem + 33024);
  unsigned short* cand = (unsigned short*)(smem + 33280);
  unsigned long long* best = (unsigned long long*)(smem + 35328);

  const int tid = threadIdx.x;
  const int blk = blockIdx.x;
  const int n0 = blk * 64;
  const int bb = blk >> 4;
  const int hw0 = (blk & 15) * 64;
  const float* zb = z + bb * 262144 + hw0;

  if (tid < 64) { runminU[tid] = 0x7F800000u; cnt[tid] = 0; }

  {  // A stage: convert z tile to f16, swizzled rows
    const int p = tid & 63, dh = tid >> 6;
    #pragma unroll
    for (int dq = 0; dq < 8; ++dq) {
      const int d0 = dh * 64 + dq * 8;
      f16x8 hv;
      #pragma unroll
      for (int j = 0; j < 8; ++j) hv[j] = (_Float16)zb[(d0 + j) * 1024 + p];
      *(f16x8*)&smem[p * 512 + ((d0 * 2) ^ ((p & 7) * 16))] = hv;
    }
  }

  const int l = tid & 63;
  const int ln = l & 15;
  const int q = l >> 4;
  const int wc = tid >> 6;        // wave: codes wc*64 .. +63 per chunk
  const int xr = (l & 7) * 16;

  float z2r[4][4];
  #pragma unroll
  for (int fi = 0; fi < 4; ++fi)
    #pragma unroll
    for (int rg = 0; rg < 4; ++rg)
      z2r[fi][rg] = z2[n0 + fi * 16 + q * 4 + rg];

  f32x4 acc[4][4];
  #pragma unroll
  for (int fi = 0; fi < 4; ++fi)
    #pragma unroll
    for (int fj = 0; fj < 4; ++fj) acc[fi][fj] = (f32x4){0.f, 0.f, 0.f, 0.f};

  __syncthreads();

  for (int cc = 0; cc < 4; ++cc) {
    const _Float16* Ebase = Ef + (cc * 256 + wc * 64 + ln) * 256 + q * 8;
    f16x8 bFb[2][4];
    #pragma unroll
    for (int fj = 0; fj < 4; ++fj)   // prologue: phase-0 B fragments
      bFb[0][fj] = *(const f16x8*)(Ebase + fj * 16 * 256);
    #pragma unroll
    for (int ph = 0; ph < 8; ++ph) {
      const int cur = ph & 1, nxt = cur ^ 1;
      if (ph < 7) {  // issue next phase's B loads before this phase's MFMAs
        #pragma unroll
        for (int fj = 0; fj < 4; ++fj)
          bFb[nxt][fj] = *(const f16x8*)(Ebase + fj * 16 * 256 + (ph + 1) * 32);
      }
      f16x8 aF[4];
      const int ab = (ph * 64 + q * 16) ^ xr;
      #pragma unroll
      for (int fi = 0; fi < 4; ++fi)
        aF[fi] = *(const f16x8*)&smem[(fi * 16 + ln) * 512 + ab];
      #pragma unroll
      for (int fi = 0; fi < 4; ++fi)
        #pragma unroll
        for (int fj = 0; fj < 4; ++fj)
          acc[fi][fj] = __builtin_amdgcn_mfma_f32_16x16x32_f16(
              aF[fi], bFb[cur][fj], acc[fi][fj], 0, 0, 0);
    }
    {  // chunk epilogue: exact prefix-min via one barrier
      const int cbase = cc * 256 + wc * 64 + ln;
      float e2v[4];
      #pragma unroll
      for (int fj = 0; fj < 4; ++fj) e2v[fj] = e2[cbase + fj * 16];
      #pragma unroll
      for (int fi = 0; fi < 4; ++fi) {
        #pragma unroll
        for (int rg = 0; rg < 4; ++rg) {
          float rm = 3.4e38f;
          #pragma unroll
          for (int fj = 0; fj < 4; ++fj)
            rm = fminf(rm, fmaf(-2.f, acc[fi][fj][rg], z2r[fi][rg] + e2v[fj]));
          rm = fminf(rm, __shfl_xor(rm, 1));
          rm = fminf(rm, __shfl_xor(rm, 2));
          rm = fminf(rm, __shfl_xor(rm, 4));
          rm = fminf(rm, __shfl_xor(rm, 8));
          if (ln == 0)
            atomicMin(&runminU[fi * 16 + q * 4 + rg], __float_as_uint(rm));
        }
      }
      __syncthreads();  // runminU now = true min over ALL codes up to chunk cc
      #pragma unroll
      for (int fi = 0; fi < 4; ++fi) {
        #pragma unroll
        for (int rg = 0; rg < 4; ++rg) {
          const int row = fi * 16 + q * 4 + rg;
          const float thr = __uint_as_float(runminU[row]) + VQ_W;
          #pragma unroll
          for (int fj = 0; fj < 4; ++fj) {
            const float sv = fmaf(-2.f, acc[fi][fj][rg], z2r[fi][rg] + e2v[fj]);
            if (sv <= thr) {
              const int slot = atomicAdd(&cnt[row], 1);
              if (slot < 16)
                cand[row * 16 + slot] = (unsigned short)(cbase + fj * 16);
            }
          }
        }
        #pragma unroll
        for (int fj = 0; fj < 4; ++fj) acc[fi][fj] = (f32x4){0.f, 0.f, 0.f, 0.f};
      }
    }
  }

  __syncthreads();
  // ---- fused rescore tail ----
  if (tid < 64) best[tid] = ~0ULL;
  __syncthreads();
  {
    const int pt = tid >> 2;   // point 0..63
    const int sl = tid & 3;    // candidate lane 0..3
    const int c = cnt[pt];
    if (c >= 2) {
      const int n = n0 + pt;
      const float z2n = z2[n];
      const float* zrow = zb + pt;  // stride-1024 rows, L1/L2-hot from A-stage
      if (c <= 16) {
        for (int s = sl; s < c; s += 4) {
          const int k = cand[pt * 16 + s];
          const float4* ep4 = (const float4*)(emb + k * 256);
          float a = 0.f;
          #pragma unroll 8
          for (int d4 = 0; d4 < 64; ++d4) {  // r20-exact sequential chain
            const float4 ev = ep4[d4];
            a = fmaf(zrow[(d4 * 4 + 0) * 1024], ev.x, a);
            a = fmaf(zrow[(d4 * 4 + 1) * 1024], ev.y, a);
            a = fmaf(zrow[(d4 * 4 + 2) * 1024], ev.z, a);
            a = fmaf(zrow[(d4 * 4 + 3) * 1024], ev.w, a);
          }
          const float sv = fmaf(-2.f, a, z2n + e2[k]);
          const unsigned long long key =
              ((unsigned long long)__float_as_uint(sv) << 10) | (unsigned)k;
          atomicMin(&best[pt], key);
        }
      } else {  // overflow fallback: exact full scan
        for (int k = sl; k < 1024; k += 4) {
          const float4* ep4 = (const float4*)(emb + k * 256);
          float a = 0.f;
          #pragma unroll 8
          for (int d4 = 0; d4 < 64; ++d4) {
            const float4 ev = ep4[d4];
            a = fmaf(zrow[(d4 * 4 + 0) * 1024], ev.x, a);
            a = fmaf(zrow[(d4 * 4 + 1) * 1024], ev.y, a);
            a = fmaf(zrow[(d4 * 4 + 2) * 1024], ev.z, a);
            a = fmaf(zrow[(d4 * 4 + 3) * 1024], ev.w, a);
          }
          const float sv = fmaf(-2.f, a, z2n + e2[k]);
          const unsigned long long key =
              ((unsigned long long)__float_as_uint(sv) << 10) | (unsigned)k;
          atomicMin(&best[pt], key);
        }
      }
    }
  }
  __syncthreads();
  if (tid < 64) {
    const int v = (cnt[tid] == 1) ? (int)cand[tid * 16]
                                  : (int)(best[tid] & 1023ULL);
    widx[n0 + tid] = v;
    out[16777217 + n0 + tid] = (float)v;
  }
}

// vq_out2 v2 (r20-verified): d-major sequential stream; reg idx; reg-staged
// zv; per-block partial loss (no global atomics).
__global__ __launch_bounds__(256) void vq_out2(
    const float* __restrict__ z, const float* __restrict__ embT,
    const int* __restrict__ widx, float* __restrict__ out,
    double* __restrict__ partial) {
  __shared__ __align__(16) float et[4 * 1024];
  __shared__ double wv[4];
  const int tid = threadIdx.x;
  const int bb = blockIdx.x >> 6;
  const int d0 = (blockIdx.x & 63) * 4;

  const int4 myi = *(const int4*)&widx[bb * 1024 + tid * 4];
  #pragma unroll
  for (int it = 0; it < 4; ++it)
    *(float4*)&et[it * 1024 + tid * 4] =
        *(const float4*)&embT[(d0 + it) * 1024 + tid * 4];

  const float* zb = z + bb * 262144 + d0 * 1024 + tid * 4;
  float* ob = out + bb * 262144 + d0 * 1024 + tid * 4;
  float4 zv[4];
  #pragma unroll
  for (int dr = 0; dr < 4; ++dr) zv[dr] = *(const float4*)&zb[dr * 1024];
  __syncthreads();

  double ls = 0.0;
  #pragma unroll
  for (int dr = 0; dr < 4; ++dr) {
    const float* etr = &et[dr * 1024];
    float4 qv;
    qv.x = etr[myi.x];
    qv.y = etr[myi.y];
    qv.z = etr[myi.z];
    qv.w = etr[myi.w];
    float dx = qv.x - zv[dr].x, dy = qv.y - zv[dr].y;
    float dz = qv.z - zv[dr].z, dw = qv.w - zv[dr].w;
    asm volatile("" : "+v"(dx), "+v"(dy), "+v"(dz), "+v"(dw));
    float4 ov;
    ov.x = zv[dr].x + dx; ov.y = zv[dr].y + dy;
    ov.z = zv[dr].z + dz; ov.w = zv[dr].w + dw;
    *(float4*)&ob[dr * 1024] = ov;
    ls += (double)dx * dx + (double)dy * dy + (double)dz * dz + (double)dw * dw;
  }
  #pragma unroll
  for (int off = 32; off > 0; off >>= 1) ls += __shfl_down(ls, off);
  if ((tid & 63) == 0) wv[tid >> 6] = ls;
  __syncthreads();
  if (tid == 0)
    partial[blockIdx.x] = ((wv[0] + wv[1]) + (wv[2] + wv[3]));
}

// Final: reduce 4096 per-block partials (fixed order) -> loss scalar.
__global__ __launch_bounds__(256) void vq_fin(const double* __restrict__ partial,
                                              float* __restrict__ out) {
  __shared__ double sd[4];
  const int tid = threadIdx.x;
  double s = 0.0;
  #pragma unroll 4
  for (int i = tid; i < 4096; i += 256) s += partial[i];
  #pragma unroll
  for (int off = 32; off > 0; off >>= 1) s += __shfl_down(s, off);
  if ((tid & 63) == 0) sd[tid >> 6] = s;
  __syncthreads();
  if (tid == 0)
    out[16777216] =
        (float)(1.25 * ((sd[0] + sd[1]) + (sd[2] + sd[3])) * (1.0 / 16777216.0));
}

extern "C" void kernel_launch(void* const* d_in, const int* in_sizes, int n_in,
                              void* d_out, int out_size, void* d_ws, size_t ws_size,
                              hipStream_t stream) {
  const float* z = (const float*)d_in[0];
  const float* emb = (const float*)d_in[1];
  float* out = (float*)d_out;
  char* ws = (char*)d_ws;
  int* widx = (int*)(ws + 64);
  float* e2 = (float*)(ws + 262208);
  float* z2 = (float*)(ws + 266304);
  _Float16* Ef = (_Float16*)(ws + 2887744);
  float* embT = (float*)(ws + 3412032);
  double* partial = (double*)(ws + 4460608);

  hipFuncSetAttribute(reinterpret_cast<const void*>(vq_screen),
                      hipFuncAttributeMaxDynamicSharedMemorySize, SCR_LDS_BYTES);

  vq_pre<<<2048, 256, 0, stream>>>(emb, z, Ef, embT, e2, z2);
  vq_screen<<<1024, 256, SCR_LDS_BYTES, stream>>>(z, emb, Ef, e2, z2, widx, out);
  vq_out2<<<4096, 256, 0, stream>>>(z, embT, widx, out, partial);
  vq_fin<<<1, 256, 0, stream>>>(partial, out);
}

// Round 26
// 194.600 us; speedup vs baseline: 1.0305x; 1.0305x over previous
//
#include <hip/hip_runtime.h>

// VectorQuantizer on MI355X — round 26: r24 composition, screen inner loop
// reverted to r12-exact (direct in-phase B loads; measured 101.6us vs the
// manual 2-buffer ring's 107us — compiler scheduling wins).
// z: (64,256,32,32) f32; emb: (1024,256) f32.
// out (f32): [0,16777216) z_q_out | [16777216] loss | [16777217,+65536) indices
//
// ws layout (bytes):
//   64       int      widx[65536]
//   262208   float    e2[1024]
//   266304   float    z2[65536]
//   528448   int      gcnt[65536]
//   790592   ushort   gcand[65536*16]
//   2887744  _Float16 Ef[1024*256]
//   3412032  float    embT[256*1024]
//   4460608  double   partial[4096]

typedef _Float16 f16x8 __attribute__((ext_vector_type(8)));
typedef float f32x4 __attribute__((ext_vector_type(4)));

#define VQ_W 1.5e-3f
#define SCR_LDS_BYTES 35328
#define RES_LDS_BYTES 33792

// fl32(v*v) with a barrier so the product cannot be contracted into a later add.
__device__ __forceinline__ float sq_rnd(float v) {
  float y = v * v;
  asm volatile("" : "+v"(y));
  return y;
}

// numpy pairwise_sum over 256 fp32 squared terms (8-accumulator blocks of 128).
__device__ float np_pw256_sq(const float* base, int stride) {
  float tot0, tot1;
  {
    const float* a = base;
    float r[8];
    #pragma unroll
    for (int j = 0; j < 8; ++j) r[j] = sq_rnd(a[j * stride]);
    #pragma unroll 1
    for (int i = 8; i < 128; i += 8) {
      #pragma unroll
      for (int j = 0; j < 8; ++j) r[j] += sq_rnd(a[(i + j) * stride]);
    }
    tot0 = ((r[0] + r[1]) + (r[2] + r[3])) + ((r[4] + r[5]) + (r[6] + r[7]));
  }
  {
    const float* a = base + 128 * stride;
    float r[8];
    #pragma unroll
    for (int j = 0; j < 8; ++j) r[j] = sq_rnd(a[j * stride]);
    #pragma unroll 1
    for (int i = 8; i < 128; i += 8) {
      #pragma unroll
      for (int j = 0; j < 8; ++j) r[j] += sq_rnd(a[(i + j) * stride]);
    }
    tot1 = ((r[0] + r[1]) + (r[2] + r[3])) + ((r[4] + r[5]) + (r[6] + r[7]));
  }
  return tot0 + tot1;
}

// Preprocessing (r23/r24-verified): blocks [0,1024) = emb->f16 + f32 transpose
// + e2; blocks [1024,2048) = z2 float4-vectorized chain-split (bit-exact).
__global__ __launch_bounds__(256) void vq_pre(const float* __restrict__ emb,
                                              const float* __restrict__ z,
                                              _Float16* __restrict__ Ef,
                                              float* __restrict__ embT,
                                              float* __restrict__ e2,
                                              float* __restrict__ z2) {
  __shared__ float smz[1024];  // [chain 16][point 64]
  const int tid = threadIdx.x;
  if (blockIdx.x < 1024) {
    const int g = blockIdx.x * 256 + tid;  // 0..262143
    const float v = emb[g];
    Ef[g] = (_Float16)v;                   // RNE v_cvt_f16_f32
    const int k = g >> 8, d = g & 255;
    embT[d * 1024 + k] = v;                // f32 transpose (exact copy)
    if (g < 1024) e2[g] = np_pw256_sq(emb + g * 256, 1);
    return;
  }
  const int blk = blockIdx.x - 1024;  // 0..1023, 64 points each
  const int n0 = blk * 64;
  const int bb = n0 >> 10, hw0 = n0 & 1023;
  const int slot = tid & 15;          // points slot*4..+3
  const int c = tid >> 4;             // chain 0..15
  const int dbase = (c >> 3) * 128 + (c & 7);
  const float* zb4 = z + bb * 262144 + hw0 + slot * 4;
  float r0 = 0.f, r1 = 0.f, r2 = 0.f, r3 = 0.f;
  #pragma unroll
  for (int i = 0; i < 16; ++i) {
    const float4 v = *(const float4*)&zb4[(dbase + 8 * i) * 1024];
    r0 += sq_rnd(v.x); r1 += sq_rnd(v.y); r2 += sq_rnd(v.z); r3 += sq_rnd(v.w);
  }
  smz[c * 64 + slot * 4 + 0] = r0;
  smz[c * 64 + slot * 4 + 1] = r1;
  smz[c * 64 + slot * 4 + 2] = r2;
  smz[c * 64 + slot * 4 + 3] = r3;
  __syncthreads();
  if (tid < 64) {
    const int p = tid;
    float h0[8], h1[8];
    #pragma unroll
    for (int j = 0; j < 8; ++j) {
      h0[j] = smz[j * 64 + p];
      h1[j] = smz[(8 + j) * 64 + p];
    }
    const float tot0 = ((h0[0] + h0[1]) + (h0[2] + h0[3])) +
                       ((h0[4] + h0[5]) + (h0[6] + h0[7]));
    const float tot1 = ((h1[0] + h1[1]) + (h1[2] + h1[3])) +
                       ((h1[4] + h1[5]) + (h1[6] + h1[7]));
    z2[n0 + p] = tot0 + tot1;
  }
}

// Screening (r12-exact inner loop, measured 101.6us): 64 pts/block, B read
// directly from L2-resident Ef inside each phase (compiler-scheduled).
// Chunk epilogue: exact prefix-min via one barrier (r9-verified superset).
__global__ __launch_bounds__(256, 4) void vq_screen(
    const float* __restrict__ z, const _Float16* __restrict__ Ef,
    const float* __restrict__ e2, const float* __restrict__ z2,
    int* __restrict__ gcnt, unsigned short* __restrict__ gcand) {
  extern __shared__ __align__(16) char smem[];
  // [0,32768) A; 32768 runminU[64]; 33024 cnt[64]; 33280 cand[64][16]
  unsigned* runminU = (unsigned*)(smem + 32768);
  int* cnt = (int*)(smem + 33024);
  unsigned short* cand = (unsigned short*)(smem + 33280);

  const int tid = threadIdx.x;
  const int blk = blockIdx.x;
  const int n0 = blk * 64;
  const int bb = blk >> 4;
  const int hw0 = (blk & 15) * 64;
  const float* zb = z + bb * 262144 + hw0;

  if (tid < 64) { runminU[tid] = 0x7F800000u; cnt[tid] = 0; }

  {  // A stage: convert z tile to f16, swizzled rows
    const int p = tid & 63, dh = tid >> 6;
    #pragma unroll
    for (int dq = 0; dq < 8; ++dq) {
      const int d0 = dh * 64 + dq * 8;
      f16x8 hv;
      #pragma unroll
      for (int j = 0; j < 8; ++j) hv[j] = (_Float16)zb[(d0 + j) * 1024 + p];
      *(f16x8*)&smem[p * 512 + ((d0 * 2) ^ ((p & 7) * 16))] = hv;
    }
  }

  const int l = tid & 63;
  const int ln = l & 15;
  const int q = l >> 4;
  const int wc = tid >> 6;        // wave: codes wc*64 .. +63 per chunk
  const int xr = (l & 7) * 16;

  float z2r[4][4];
  #pragma unroll
  for (int fi = 0; fi < 4; ++fi)
    #pragma unroll
    for (int rg = 0; rg < 4; ++rg)
      z2r[fi][rg] = z2[n0 + fi * 16 + q * 4 + rg];

  f32x4 acc[4][4];
  #pragma unroll
  for (int fi = 0; fi < 4; ++fi)
    #pragma unroll
    for (int fj = 0; fj < 4; ++fj) acc[fi][fj] = (f32x4){0.f, 0.f, 0.f, 0.f};

  __syncthreads();

  for (int p = 0; p < 32; ++p) {
    const int ph = p & 7;
    const int cc = p >> 3;
    {  // compute phase p: B direct from L2, A from LDS
      const _Float16* Eb =
          Ef + (cc * 256 + wc * 64 + ln) * 256 + ph * 32 + q * 8;
      f16x8 aF[4], bF[4];
      #pragma unroll
      for (int fj = 0; fj < 4; ++fj)
        bF[fj] = *(const f16x8*)(Eb + fj * 16 * 256);
      const int ab = (ph * 64 + q * 16) ^ xr;
      #pragma unroll
      for (int fi = 0; fi < 4; ++fi)
        aF[fi] = *(const f16x8*)&smem[(fi * 16 + ln) * 512 + ab];
      #pragma unroll
      for (int fi = 0; fi < 4; ++fi)
        #pragma unroll
        for (int fj = 0; fj < 4; ++fj)
          acc[fi][fj] = __builtin_amdgcn_mfma_f32_16x16x32_f16(
              aF[fi], bF[fj], acc[fi][fj], 0, 0, 0);
    }
    if (ph == 7) {  // chunk epilogue: exact prefix-min via one barrier
      const int cbase = cc * 256 + wc * 64 + ln;
      float e2v[4];
      #pragma unroll
      for (int fj = 0; fj < 4; ++fj) e2v[fj] = e2[cbase + fj * 16];
      #pragma unroll
      for (int fi = 0; fi < 4; ++fi) {
        #pragma unroll
        for (int rg = 0; rg < 4; ++rg) {
          float rm = 3.4e38f;
          #pragma unroll
          for (int fj = 0; fj < 4; ++fj)
            rm = fminf(rm, fmaf(-2.f, acc[fi][fj][rg], z2r[fi][rg] + e2v[fj]));
          rm = fminf(rm, __shfl_xor(rm, 1));
          rm = fminf(rm, __shfl_xor(rm, 2));
          rm = fminf(rm, __shfl_xor(rm, 4));
          rm = fminf(rm, __shfl_xor(rm, 8));
          if (ln == 0)
            atomicMin(&runminU[fi * 16 + q * 4 + rg], __float_as_uint(rm));
        }
      }
      __syncthreads();  // runminU now = true min over ALL codes up to chunk cc
      #pragma unroll
      for (int fi = 0; fi < 4; ++fi) {
        #pragma unroll
        for (int rg = 0; rg < 4; ++rg) {
          const int row = fi * 16 + q * 4 + rg;
          const float thr = __uint_as_float(runminU[row]) + VQ_W;
          #pragma unroll
          for (int fj = 0; fj < 4; ++fj) {
            const float sv = fmaf(-2.f, acc[fi][fj][rg], z2r[fi][rg] + e2v[fj]);
            if (sv <= thr) {
              const int slot = atomicAdd(&cnt[row], 1);
              if (slot < 16)
                cand[row * 16 + slot] = (unsigned short)(cbase + fj * 16);
            }
          }
        }
        #pragma unroll
        for (int fj = 0; fj < 4; ++fj) acc[fi][fj] = (f32x4){0.f, 0.f, 0.f, 0.f};
      }
    }
  }

  __syncthreads();
  if (tid < 64) gcnt[n0 + tid] = cnt[tid];
  {
    const int rr = tid >> 2, si = (tid & 3) * 4;
    *(uint2*)&gcand[(n0 + rr) * 16 + si] = *(const uint2*)&cand[rr * 16 + si];
  }
}

// Rescore (r20-exact, r17/r19-verified): 32 pts/block, grid 2048.
// z tile float4-staged to LDS (bit-exact), 8 threads/point, float4 emb chain
// (exact fmaf order), u64 atomicMin merge (LDS-local). Writes widx + indices.
__global__ __launch_bounds__(256, 4) void vq_rescore(
    const float* __restrict__ z, const float* __restrict__ emb,
    const float* __restrict__ e2, const float* __restrict__ z2,
    const int* __restrict__ gcnt, const unsigned short* __restrict__ gcand,
    int* __restrict__ widx, float* __restrict__ out) {
  extern __shared__ __align__(16) char psmem[];
  // zt[32][257] f32 (32896B); 33536 best[32] u64
  float* zt = (float*)psmem;
  unsigned long long* best = (unsigned long long*)(psmem + 33536);

  const int tid = threadIdx.x;
  const int pg = tid & 7;
  const int ds = tid >> 3;
  const int w8 = tid >> 5;
  const int l = tid & 31;
  const int n0 = blockIdx.x << 5;
  const int bb = n0 >> 10, hw0 = n0 & 1023;
  const int n = n0 + l;

  const int c = gcnt[n];
  const bool need = __any(c >= 2);  // wave-uniform

  if (!need) {
    if (tid < 32) {
      const int v = gcand[(n0 + tid) * 16];
      widx[n0 + tid] = v;
      out[16777217 + n0 + tid] = (float)v;
    }
    return;
  }

  {  // stage z tile: 8 float4 loads staged, then scatter to zt rows
    const float* zb = z + bb * 262144 + hw0 + pg * 4;
    float4 zS[8];
    #pragma unroll
    for (int jj = 0; jj < 8; ++jj) zS[jj] = *(const float4*)&zb[(ds * 8 + jj) * 1024];
    #pragma unroll
    for (int jj = 0; jj < 8; ++jj) {
      const int d = ds * 8 + jj;
      zt[(pg * 4 + 0) * 257 + d] = zS[jj].x;
      zt[(pg * 4 + 1) * 257 + d] = zS[jj].y;
      zt[(pg * 4 + 2) * 257 + d] = zS[jj].z;
      zt[(pg * 4 + 3) * 257 + d] = zS[jj].w;
    }
  }
  if (tid < 32) best[tid] = ~0ULL;
  __syncthreads();

  if (c >= 2) {
    const float z2n = z2[n];
    const float* zrow = &zt[l * 257];
    if (c <= 16) {
      for (int s = w8; s < c; s += 8) {
        const int k = gcand[n * 16 + s];
        const float4* ep4 = (const float4*)(emb + k * 256);
        float a = 0.f;
        #pragma unroll 8
        for (int d4 = 0; d4 < 64; ++d4) {  // float4 emb loads; chain order exact
          const float4 ev = ep4[d4];
          a = fmaf(zrow[d4 * 4 + 0], ev.x, a);
          a = fmaf(zrow[d4 * 4 + 1], ev.y, a);
          a = fmaf(zrow[d4 * 4 + 2], ev.z, a);
          a = fmaf(zrow[d4 * 4 + 3], ev.w, a);
        }
        const float sv = fmaf(-2.f, a, z2n + e2[k]);
        const unsigned long long key =
            ((unsigned long long)__float_as_uint(sv) << 10) | (unsigned)k;
        atomicMin(&best[l], key);
      }
    } else {  // overflow fallback: exact full scan
      for (int k = w8; k < 1024; k += 8) {
        const float4* ep4 = (const float4*)(emb + k * 256);
        float a = 0.f;
        #pragma unroll 8
        for (int d4 = 0; d4 < 64; ++d4) {
          const float4 ev = ep4[d4];
          a = fmaf(zrow[d4 * 4 + 0], ev.x, a);
          a = fmaf(zrow[d4 * 4 + 1], ev.y, a);
          a = fmaf(zrow[d4 * 4 + 2], ev.z, a);
          a = fmaf(zrow[d4 * 4 + 3], ev.w, a);
        }
        const float sv = fmaf(-2.f, a, z2n + e2[k]);
        const unsigned long long key =
            ((unsigned long long)__float_as_uint(sv) << 10) | (unsigned)k;
        atomicMin(&best[l], key);
      }
    }
  }
  __syncthreads();
  if (tid < 32) {
    const int cc = gcnt[n0 + tid];
    const int v = (cc == 1) ? (int)gcand[(n0 + tid) * 16]
                            : (int)(best[tid] & 1023ULL);
    widx[n0 + tid] = v;
    out[16777217 + n0 + tid] = (float)v;
  }
}

// vq_out2 v2 (r20-verified): d-major sequential stream; reg idx; reg-staged
// zv; per-block partial loss (no global atomics).
__global__ __launch_bounds__(256) void vq_out2(
    const float* __restrict__ z, const float* __restrict__ embT,
    const int* __restrict__ widx, float* __restrict__ out,
    double* __restrict__ partial) {
  __shared__ __align__(16) float et[4 * 1024];
  __shared__ double wv[4];
  const int tid = threadIdx.x;
  const int bb = blockIdx.x >> 6;
  const int d0 = (blockIdx.x & 63) * 4;

  const int4 myi = *(const int4*)&widx[bb * 1024 + tid * 4];
  #pragma unroll
  for (int it = 0; it < 4; ++it)
    *(float4*)&et[it * 1024 + tid * 4] =
        *(const float4*)&embT[(d0 + it) * 1024 + tid * 4];

  const float* zb = z + bb * 262144 + d0 * 1024 + tid * 4;
  float* ob = out + bb * 262144 + d0 * 1024 + tid * 4;
  float4 zv[4];
  #pragma unroll
  for (int dr = 0; dr < 4; ++dr) zv[dr] = *(const float4*)&zb[dr * 1024];
  __syncthreads();

  double ls = 0.0;
  #pragma unroll
  for (int dr = 0; dr < 4; ++dr) {
    const float* etr = &et[dr * 1024];
    float4 qv;
    qv.x = etr[myi.x];
    qv.y = etr[myi.y];
    qv.z = etr[myi.z];
    qv.w = etr[myi.w];
    float dx = qv.x - zv[dr].x, dy = qv.y - zv[dr].y;
    float dz = qv.z - zv[dr].z, dw = qv.w - zv[dr].w;
    asm volatile("" : "+v"(dx), "+v"(dy), "+v"(dz), "+v"(dw));
    float4 ov;
    ov.x = zv[dr].x + dx; ov.y = zv[dr].y + dy;
    ov.z = zv[dr].z + dz; ov.w = zv[dr].w + dw;
    *(float4*)&ob[dr * 1024] = ov;
    ls += (double)dx * dx + (double)dy * dy + (double)dz * dz + (double)dw * dw;
  }
  #pragma unroll
  for (int off = 32; off > 0; off >>= 1) ls += __shfl_down(ls, off);
  if ((tid & 63) == 0) wv[tid >> 6] = ls;
  __syncthreads();
  if (tid == 0)
    partial[blockIdx.x] = ((wv[0] + wv[1]) + (wv[2] + wv[3]));
}

// Final: reduce 4096 per-block partials (fixed order) -> loss scalar.
__global__ __launch_bounds__(256) void vq_fin(const double* __restrict__ partial,
                                              float* __restrict__ out) {
  __shared__ double sd[4];
  const int tid = threadIdx.x;
  double s = 0.0;
  #pragma unroll 4
  for (int i = tid; i < 4096; i += 256) s += partial[i];
  #pragma unroll
  for (int off = 32; off > 0; off >>= 1) s += __shfl_down(s, off);
  if ((tid & 63) == 0) sd[tid >> 6] = s;
  __syncthreads();
  if (tid == 0)
    out[16777216] =
        (float)(1.25 * ((sd[0] + sd[1]) + (sd[2] + sd[3])) * (1.0 / 16777216.0));
}

extern "C" void kernel_launch(void* const* d_in, const int* in_sizes, int n_in,
                              void* d_out, int out_size, void* d_ws, size_t ws_size,
                              hipStream_t stream) {
  const float* z = (const float*)d_in[0];
  const float* emb = (const float*)d_in[1];
  float* out = (float*)d_out;
  char* ws = (char*)d_ws;
  int* widx = (int*)(ws + 64);
  float* e2 = (float*)(ws + 262208);
  float* z2 = (float*)(ws + 266304);
  int* gcnt = (int*)(ws + 528448);
  unsigned short* gcand = (unsigned short*)(ws + 790592);
  _Float16* Ef = (_Float16*)(ws + 2887744);
  float* embT = (float*)(ws + 3412032);
  double* partial = (double*)(ws + 4460608);

  hipFuncSetAttribute(reinterpret_cast<const void*>(vq_screen),
                      hipFuncAttributeMaxDynamicSharedMemorySize, SCR_LDS_BYTES);
  hipFuncSetAttribute(reinterpret_cast<const void*>(vq_rescore),
                      hipFuncAttributeMaxDynamicSharedMemorySize, RES_LDS_BYTES);

  vq_pre<<<2048, 256, 0, stream>>>(emb, z, Ef, embT, e2, z2);
  vq_screen<<<1024, 256, SCR_LDS_BYTES, stream>>>(z, Ef, e2, z2, gcnt, gcand);
  vq_rescore<<<2048, 256, RES_LDS_BYTES, stream>>>(z, emb, e2, z2, gcnt, gcand,
                                                   widx, out);
  vq_out2<<<4096, 256, 0, stream>>>(z, embT, widx, out, partial);
  vq_fin<<<1, 256, 0, stream>>>(partial, out);
}